// Round 10
// baseline (222.543 us; speedup 1.0000x reference)
//
#include <hip/hip_runtime.h>

// FocalCTCLoss on MI355X — round 15: global_load_lds scatter-gather + split
// streaming. B=256, T=1024, V=128 (BLANK=127), L=64, S=129.
//
// r14 post-mortem: DP critical path = 33 phases x ~5760 cy = 79 us. Cause:
// per-lane scalar gather loads (stride 512 B) sunk to depth ~2-3 by the
// compiler => ~16x900/3 cy per phase. Same mechanism explains r5/r9/r10/r13
// (all 45-92 us). Also confirmed: one resident block per CU caps streaming
// at ~40 lines in flight => 512 KB/row needs 77 us (the r5/r13 plateau) —
// per-row streaming MUST spread across CUs (keep the denom split).
//
// Fix: the gather never touches VGPRs. __builtin_amdgcn_global_load_lds
// has a PER-LANE global source address and a wave-uniform LDS dest
// (base+lane*4): ONE instruction gathers u[t][lab_lane] for all 64 lanes
// into garr[t][0..63]. 22 instructions/wave all in flight; one vmcnt drain
// per phase (__syncthreads). Blanks: one instruction, per-lane t.
// Consumer: batched 16-deep LDS prefetch (grouped loads -> grouped uses).
// Three launches: denom (streams + warms L3) -> dp (L3-warm gather) ->
// finalize. Numerics identical to r14 (passed, absmax 16 < 23.2).

#define EPSF 1e-7f

constexpr int Bb   = 256;
constexpr int Tt   = 1024;
constexpr int Vv   = 128;
constexpr int Ll   = 64;
constexpr int CH   = 64;          // timesteps per chunk (dp)
constexpr int NCH  = Tt / CH;     // 16 chunks
constexpr int NPH  = NCH + 1;     // 17 phases (gather p / consume p-1)
constexpr int NSEG = 8;           // denom segments per batch row

// ---- DPP helpers -----------------------------------------------------------
template <int Ctrl, int RowMask, int BankMask, bool BoundCtrl>
__device__ __forceinline__ float dppf(float x) {
    return __int_as_float(__builtin_amdgcn_update_dpp(
        0, __float_as_int(x), Ctrl, RowMask, BankMask, BoundCtrl));
}

// Half-wave sums: lane 31 = sum(lanes 0..31), lane 63 = sum(lanes 32..63).
__device__ __forceinline__ float half_sum(float x) {
    x += dppf<0x111, 0xf, 0xf, true>(x);
    x += dppf<0x112, 0xf, 0xf, true>(x);
    x += dppf<0x114, 0xf, 0xf, true>(x);
    x += dppf<0x118, 0xf, 0xf, true>(x);
    x += dppf<0x142, 0xa, 0xf, false>(x);
    return x;
}

// Wave-64 max (non-negative inputs), valid on lane 63.
__device__ __forceinline__ float wave_max63(float x) {
    x = fmaxf(x, dppf<0x111, 0xf, 0xf, true>(x));
    x = fmaxf(x, dppf<0x112, 0xf, 0xf, true>(x));
    x = fmaxf(x, dppf<0x114, 0xf, 0xf, true>(x));
    x = fmaxf(x, dppf<0x118, 0xf, 0xf, true>(x));
    x = fmaxf(x, dppf<0x142, 0xa, 0xf, false>(x));
    x = fmaxf(x, dppf<0x143, 0xc, 0xf, false>(x));
    return x;
}

__device__ __forceinline__ float bcast63(float x) {
    return __int_as_float(__builtin_amdgcn_readlane(__float_as_int(x), 63));
}

// ---- DP step (textual; updates a_even/a_odd/a128/eacc in enclosing scope) --
#define DO_STEP(QE, QB, CHK)                                                 \
    do {                                                                     \
        const float am1_ = dppf<0x138, 0xf, 0xf, true>(a_odd);               \
        const float ne_  = (a_even + am1_) * (QB);                           \
        const float no_  = fmaf(maskf, am1_, a_odd + a_even) * (QE);         \
        const float n1_  = (a128 + a_odd) * (QB);                            \
        a_even = ne_; a_odd = no_; a128 = n1_;                               \
        if (CHK) {                                                           \
            const float m_ = fmaxf(fmaxf(a_even, a_odd), a128);              \
            if (__all(m_ < 0x1p-75f)) {                                      \
                const float    wmax_  = bcast63(wave_max63(m_));             \
                const unsigned e_     = __float_as_uint(wmax_) >> 23;        \
                const float    scale_ = __uint_as_float((254u - e_) << 23);  \
                eacc += (int)e_ - 127;                                       \
                a_even *= scale_; a_odd *= scale_; a128 *= scale_;           \
            }                                                                \
        }                                                                    \
    } while (0)

// ---- async gather: per-lane global src -> LDS base+lane*4 ------------------
#define GL_LDS(GP, LP)                                                       \
    __builtin_amdgcn_global_load_lds(                                        \
        (const __attribute__((address_space(1))) unsigned int*)(GP),         \
        (__attribute__((address_space(3))) unsigned int*)(LP), 4, 0, 0)

// ---- consumer helper macros (all names static; no arrays) ------------------
#define CONS4(Q0, Q1, Q2, Q3, BF, LAST)                                      \
    DO_STEP((Q0) + EPSF, BF.x + EPSF, false);                                \
    DO_STEP((Q1) + EPSF, BF.y + EPSF, false);                                \
    DO_STEP((Q2) + EPSF, BF.z + EPSF, false);                                \
    DO_STEP((Q3) + EPSF, BF.w + EPSF, LAST);

#define LOADA(TB)                                                            \
    la0  = G[(TB + 0)  * 64 + lane]; la1  = G[(TB + 1)  * 64 + lane];        \
    la2  = G[(TB + 2)  * 64 + lane]; la3  = G[(TB + 3)  * 64 + lane];        \
    la4  = G[(TB + 4)  * 64 + lane]; la5  = G[(TB + 5)  * 64 + lane];        \
    la6  = G[(TB + 6)  * 64 + lane]; la7  = G[(TB + 7)  * 64 + lane];        \
    la8  = G[(TB + 8)  * 64 + lane]; la9  = G[(TB + 9)  * 64 + lane];        \
    la10 = G[(TB + 10) * 64 + lane]; la11 = G[(TB + 11) * 64 + lane];        \
    la12 = G[(TB + 12) * 64 + lane]; la13 = G[(TB + 13) * 64 + lane];        \
    la14 = G[(TB + 14) * 64 + lane]; la15 = G[(TB + 15) * 64 + lane];        \
    pa0 = BL[(TB) / 4 + 0]; pa1 = BL[(TB) / 4 + 1];                          \
    pa2 = BL[(TB) / 4 + 2]; pa3 = BL[(TB) / 4 + 3];

#define LOADB(TB)                                                            \
    lb0  = G[(TB + 0)  * 64 + lane]; lb1  = G[(TB + 1)  * 64 + lane];        \
    lb2  = G[(TB + 2)  * 64 + lane]; lb3  = G[(TB + 3)  * 64 + lane];        \
    lb4  = G[(TB + 4)  * 64 + lane]; lb5  = G[(TB + 5)  * 64 + lane];        \
    lb6  = G[(TB + 6)  * 64 + lane]; lb7  = G[(TB + 7)  * 64 + lane];        \
    lb8  = G[(TB + 8)  * 64 + lane]; lb9  = G[(TB + 9)  * 64 + lane];        \
    lb10 = G[(TB + 10) * 64 + lane]; lb11 = G[(TB + 11) * 64 + lane];        \
    lb12 = G[(TB + 12) * 64 + lane]; lb13 = G[(TB + 13) * 64 + lane];        \
    lb14 = G[(TB + 14) * 64 + lane]; lb15 = G[(TB + 15) * 64 + lane];        \
    pb0 = BL[(TB) / 4 + 0]; pb1 = BL[(TB) / 4 + 1];                          \
    pb2 = BL[(TB) / 4 + 2]; pb3 = BL[(TB) / 4 + 3];

#define CONSA()                                                              \
    CONS4(la0,  la1,  la2,  la3,  pa0, false)                                \
    CONS4(la4,  la5,  la6,  la7,  pa1, false)                                \
    CONS4(la8,  la9,  la10, la11, pa2, false)                                \
    CONS4(la12, la13, la14, la15, pa3, true)

#define CONSB()                                                              \
    CONS4(lb0,  lb1,  lb2,  lb3,  pb0, false)                                \
    CONS4(lb4,  lb5,  lb6,  lb7,  pb1, false)                                \
    CONS4(lb8,  lb9,  lb10, lb11, pb2, false)                                \
    CONS4(lb12, lb13, lb14, lb15, pb3, true)

// ---- kernel 1: denominator streaming (fill-shaped MLP) ---------------------
__launch_bounds__(256, 8)
__global__ void denom_kernel(const float* __restrict__ y_pred,
                             float* __restrict__ den_ws) {
    const int idx  = blockIdx.x;
    const int b    = idx >> 3;          // 0..255
    const int seg  = idx & (NSEG - 1);  // 0..7
    const int lane = threadIdx.x & 63;
    const int wv   = threadIdx.x >> 6;

    const float4* src4 =
        (const float4*)(y_pred + (size_t)b * Tt * Vv) +
        seg * (Tt / NSEG) * (Vv / 4);
    const int h   = 2 * wv + (lane >> 5);  // half-wave 0..7
    const int c32 = lane & 31;
    float ll = 0.0f;
#pragma unroll
    for (int k = 0; k < 16; ++k) {
        const int r = h + 8 * k;  // 0..127 within segment
        const float4 v = src4[r * 32 + c32];
        const float  s = half_sum(v.x + v.y + v.z + v.w);
        if (c32 == 31) ll += __log2f(s + (float)Vv * EPSF);
    }
    __shared__ float dpart[8];
    if (c32 == 31) dpart[h] = ll;
    __syncthreads();
    if (threadIdx.x == 0) {
        den_ws[seg * Bb + b] = dpart[0] + dpart[1] + dpart[2] + dpart[3] +
                               dpart[4] + dpart[5] + dpart[6] + dpart[7];
    }
}

// ---- kernel 2: serial CTC recursion; async scatter-gather into LDS ---------
__launch_bounds__(256, 1)
__global__ void dp_kernel(const int* __restrict__ y_true,
                          const float* __restrict__ y_pred,
                          float* __restrict__ num_ws) {
    const int b    = blockIdx.x;
    const int lane = threadIdx.x & 63;
    const int wv   = threadIdx.x >> 6;  // 0..3

    const float* ygl = y_pred + (size_t)b * Tt * Vv;

    __shared__ float garr[2 * CH * 64];  // 32 KB: [buf][t][state_lane]
    __shared__ float lblk[2 * CH];       // 512 B: [buf][t] blank

    const int lab = y_true[b * Ll + lane];  // label of odd state 2*lane+1

    float a_even = 0.0f, a_odd = 0.0f, a128 = 0.0f, maskf = 0.0f;
    int   eacc = 0;
    if (wv == 0) {
        const int labp = __shfl_up(lab, 1);
        maskf  = (lane == 0 || lab != labp) ? 1.0f : 0.0f;
        a_even = (lane == 0) ? 1.0f : 0.0f;  // pre-t0 init
    }

    for (int p = 0; p < NPH; ++p) {
        if (wv >= 1) {
            // ---- gather chunk p: one global_load_lds per t (labels),
            //      one per chunk (blanks). Zero VGPR round-trip.
            if (p < NCH) {
                const int    buf = p & 1;
                const float* src = ygl + p * CH * Vv;
                float*       dst = garr + buf * CH * 64;
#pragma unroll
                for (int j = 0; j < 22; ++j) {
                    const int t = (wv - 1) + 3 * j;  // wave-uniform
                    if (t < CH) GL_LDS(src + t * Vv + lab, dst + t * 64);
                }
                if (wv == 2)  // per-lane t: lblk[buf][lane] = u[t0+lane][127]
                    GL_LDS(src + lane * Vv + (Vv - 1), lblk + buf * CH);
            }
        } else if (p > 0) {
            // ---- consume chunk p-1: 64 steps, batched 16-deep prefetch ----
            const int     buf = (p - 1) & 1;
            const float*  G   = garr + buf * CH * 64;
            const float4* BL  = (const float4*)(lblk + buf * CH);
            __builtin_amdgcn_s_setprio(1);
            float la0, la1, la2, la3, la4, la5, la6, la7;
            float la8, la9, la10, la11, la12, la13, la14, la15;
            float lb0, lb1, lb2, lb3, lb4, lb5, lb6, lb7;
            float lb8, lb9, lb10, lb11, lb12, lb13, lb14, lb15;
            float4 pa0, pa1, pa2, pa3, pb0, pb1, pb2, pb3;
            LOADA(0)
            LOADB(16)
            CONSA()        // t 0..15  (rescale check at 15)
            LOADA(32)
            CONSB()        // t 16..31 (check at 31)
            LOADB(48)
            CONSA()        // t 32..47 (check at 47)
            CONSB()        // t 48..63 (check at 63)
            __builtin_amdgcn_s_setprio(0);
        }
        __syncthreads();
    }

    if (wv == 0 && lane == 63) {
        const float tot = fmaxf(a128 + a_odd, 1e-37f);
        num_ws[b] = __log2f(tot) + (float)eacc;
    }
}

// ---- kernel 3: combine numerator/denominator, focal transform, mean --------
__global__ void finalize_kernel(const float* __restrict__ num_ws,
                                const float* __restrict__ den_ws,
                                float* __restrict__ out) {
    const int i    = threadIdx.x;  // 256 threads = 4 waves; i == b
    const int lane = i & 63;
    const int wv   = i >> 6;

    float ds = 0.0f;
#pragma unroll
    for (int k = 0; k < NSEG; ++k) ds += den_ws[k * Bb + i];

    const float log2lik = num_ws[i] - ds;
    const float ln_lik  = 0.69314718055994530942f * log2lik;
    const float loss    = -ln_lik;
    const float pp      = __expf(ln_lik);
    const float om      = 1.0f - pp;
    float f = 0.25f * om * om * loss;

#pragma unroll
    for (int off = 32; off > 0; off >>= 1) f += __shfl_xor(f, off);

    __shared__ float red[4];
    if (lane == 0) red[wv] = f;
    __syncthreads();
    if (i == 0)
        out[0] = (red[0] + red[1] + red[2] + red[3]) * (1.0f / (float)Bb);
}

extern "C" void kernel_launch(void* const* d_in, const int* in_sizes, int n_in,
                              void* d_out, int out_size, void* d_ws, size_t ws_size,
                              hipStream_t stream) {
    const int*   y_true = (const int*)d_in[0];    // [B, L] int32
    const float* y_pred = (const float*)d_in[1];  // [B, T, V] float32
    float* num_ws = (float*)d_ws;                 // [B]
    float* den_ws = num_ws + Bb;                  // [NSEG][B]

    denom_kernel<<<Bb * NSEG, 256, 0, stream>>>(y_pred, den_ws);
    dp_kernel<<<Bb, 256, 0, stream>>>(y_true, y_pred, num_ws);
    finalize_kernel<<<1, 256, 0, stream>>>(num_ws, den_ws, (float*)d_out);
}